// Round 4
// baseline (181.123 us; speedup 1.0000x reference)
//
#include <hip/hip_runtime.h>
#include <stdint.h>

#define N_ANCHORS 6144
#define NUM_CLASSES 80
#define NWORDS 96   // 6144 / 64
#define NTILES 24   // 6144 / 256
#define SCAN_B 32   // candidates per scan batch
#define ROWSTRIDE 128  // ulls per LDS row (1024B: 64 lanes x 16B global_load_lds)

// ---------------- static device scratch (avoids ws_size assumptions) ----------------
// +64 ull tail pad: global_load_lds stages 1024B per 768B row (lanes 48-63 over-read 256B on last row)
__device__ unsigned long long g_mask[(size_t)N_ANCHORS * NWORDS + 64];
__device__ float4 g_sbox[N_ANCHORS];     // sorted boxes
__device__ int    g_rpart[NTILES][N_ANCHORS]; // per-j-tile rank partials
__device__ int    g_fpart[NTILES][N_ANCHORS]; // per-j-tile filtered-index partials
__device__ int    g_sAnchor[N_ANCHORS];  // sorted pos -> anchor id
__device__ int    g_sFi[N_ANCHORS];      // sorted pos -> filtered index
__device__ int    g_F;

__device__ __forceinline__ unsigned long long shfl64(unsigned long long v, int l) {
    return __shfl(v, l, 64);
}

// key = conf[i][0] if max(conf[i][:]) > 0.5 else -1  (exact fmax tree/order preserved)
__device__ __forceinline__ float anchor_key(const float* __restrict__ conf, int i, bool& valid) {
    const float4* cp4 = (const float4*)(conf + (size_t)i * NUM_CLASSES);
    float4 v0 = cp4[0];
    float score = v0.x;
    float m = fmaxf(fmaxf(v0.x, v0.y), fmaxf(v0.z, v0.w));
    #pragma unroll
    for (int c = 1; c < NUM_CLASSES / 4; ++c) {
        float4 v = cp4[c];
        m = fmaxf(m, fmaxf(fmaxf(v.x, v.y), fmaxf(v.z, v.w)));
    }
    valid = m > 0.5f;
    return valid ? score : -1.0f;
}

// ---------------- K1: counting-sort rank partials ----------------
// rank_i = #{valid j : key_j > key_i || (key_j == key_i && j < i)}  (stable desc sort)
// fic_i  = #{valid j : j < i}
__global__ void __launch_bounds__(256) k_rank(const float* __restrict__ conf) {
    __shared__ float skey[256];
    int y = blockIdx.y;
    int j0 = y * 256;
    bool vj;
    skey[threadIdx.x] = anchor_key(conf, j0 + threadIdx.x, vj);
    int i = blockIdx.x * 256 + threadIdx.x;
    bool vi;
    float ki = anchor_key(conf, i, vi);
    __syncthreads();
    int r = 0, f = 0;
    #pragma unroll 8
    for (int jj = 0; jj < 256; ++jj) {
        float kj = skey[jj];
        int j = j0 + jj;
        bool valid_j = kj >= 0.0f;
        r += (kj > ki) || (kj == ki && j < i && valid_j);
        f += (j < i) && valid_j;
    }
    g_rpart[y][i] = r;   // plain stores: unique (y,i) per thread
    g_fpart[y][i] = f;
}

// ---------------- K2: reduce partials + scatter into sorted order (+ F, boxes) ----------------
__global__ void __launch_bounds__(256) k_scatter(const float* __restrict__ loc,
                                                 const float* __restrict__ conf,
                                                 const float* __restrict__ tb) {
    int i = blockIdx.x * 256 + threadIdx.x;
    bool vi;
    float ki = anchor_key(conf, i, vi);
    (void)ki;
    int r = 0, f = 0;
    #pragma unroll
    for (int y = 0; y < NTILES; ++y) { r += g_rpart[y][i]; f += g_fpart[y][i]; }
    if (vi) {
        float px = loc[2 * i], py = loc[2 * i + 1];
        float4 b;
        b.x = __fmul_rn(tb[0], px);
        b.y = __fmul_rn(tb[1], py);
        b.z = __fmul_rn(tb[2], px);
        b.w = __fmul_rn(tb[3], py);
        g_sbox[r] = b;
        g_sAnchor[r] = i;
        g_sFi[r] = f;
    }
    if (i == N_ANCHORS - 1) g_F = f + (vi ? 1 : 0);   // total valid count, no atomic
}

// ---------------- K3: IoU > 0.5 bitmask, upper triangle (word >= row/64) ----------------
// NOTE: the __fdiv_rn must stay — predicate must be bit-identical to XLA's
// inter/union division; a mul-compare rewrite flips ~2 expected borderline
// pairs out of 18.9M and changes the kept set.
__global__ void __launch_bounds__(256) k_mask(void) {
    int wave = (blockIdx.x * 256 + threadIdx.x) >> 6;
    int lane = threadIdx.x & 63;
    if (wave >= N_ANCHORS) return;
    int i = wave;
    float4 bi = g_sbox[i];
    float areai = __fmul_rn(bi.z - bi.x, bi.w - bi.y);
    unsigned long long* row = g_mask + (size_t)i * NWORDS;
    for (int w = (i >> 6); w < NWORDS; ++w) {
        float4 bj = g_sbox[w * 64 + lane];
        float areaj = __fmul_rn(bj.z - bj.x, bj.w - bj.y);
        float lx = fmaxf(bi.x, bj.x), ly = fmaxf(bi.y, bj.y);
        float rx = fminf(bi.z, bj.z), ry = fminf(bi.w, bj.w);
        float iw = fmaxf(rx - lx, 0.0f), ih = fmaxf(ry - ly, 0.0f);
        float inter = __fmul_rn(iw, ih);
        float denom = __fsub_rn(__fadd_rn(areai, areaj), inter);
        float iou = __fdiv_rn(inter, denom);
        unsigned long long bits = __ballot(iou > 0.5f);
        if (lane == 0) row[w] = bits;
    }
}

// ---------------- K4: single-wave greedy-NMS scan + fused loss ----------------
// r3 lesson: register row-arrays spill to scratch (VGPR=96) and the resolve chain
// serializes on private-segment loads -> 48us regardless of batch size. New shape:
//   - rows staged to LDS via global_load_lds (1 instr/row, ONE vmcnt(0) per batch)
//   - intra-batch greedy via BxB conflict matrix: serial loop is register/shfl-only
//   - kept rows folded into remv from LDS (pipelined, uniform-predicated)
//   - loss fused into the same wave (lane=class transpose, coalesced conf reads)
__global__ void __launch_bounds__(64, 1) k_scan(const float* __restrict__ conf,
                                                const float* __restrict__ tb,
                                                float* __restrict__ out) {
    __shared__ alignas(16) unsigned long long rowbuf[SCAN_B][ROWSTRIDE]; // 32 KB
    __shared__ int slots[SCAN_B];
    __shared__ int keptLds[N_ANCHORS];                                   // 24 KB
    int lane = threadIdx.x;
    int F = g_F;
    if (lane < SCAN_B) slots[lane] = 0;   // keep stale reads in-range (first batch)
    auto initw = [&](int w) -> unsigned long long {
        long long lo = (long long)w * 64, hi = lo + 64;
        if (F <= lo) return ~0ull;
        if (F >= hi) return 0ull;
        return (~0ull) << (F - lo);
    };
    unsigned long long remv0 = initw(lane);                                  // word lane
    unsigned long long remv1 = (lane < 32) ? initw(64 + lane) : ~0ull;       // word 64+lane
    unsigned long long kept0 = 0, kept1 = 0;
    int lastPos = -1;

    while (true) {
        // --- extract first SCAN_B candidate positions > lastPos under current remv ---
        unsigned long long c0 = ~remv0;
        unsigned long long c1 = (lane < 32) ? ~remv1 : 0ull;
        {
            long long lo = (long long)lane << 6;
            if (lastPos >= lo + 63)      c0 = 0ull;
            else if (lastPos >= lo)      c0 &= (~0ull) << (int)(lastPos - lo + 1);
        }
        if (lane < 32) {
            long long lo = (long long)(64 + lane) << 6;
            if (lastPos >= lo + 63)      c1 = 0ull;
            else if (lastPos >= lo)      c1 &= (~0ull) << (int)(lastPos - lo + 1);
        }
        int n0 = __popcll(c0), n1 = __popcll(c1);
        int x0 = n0, x1 = n1;
        for (int ofs = 1; ofs < 64; ofs <<= 1) {
            int y0 = __shfl_up(x0, ofs, 64);
            int y1 = __shfl_up(x1, ofs, 64);
            if (lane >= ofs) { x0 += y0; x1 += y1; }
        }
        int tot0 = __shfl(x0, 63, 64);
        int tot1 = __shfl(x1, 63, 64);
        int total = tot0 + tot1;
        if (total == 0) break;
        int nb = (total < SCAN_B) ? total : SCAN_B;
        int off0 = x0 - n0;
        int off1 = tot0 + (x1 - n1);
        {
            unsigned long long wd = c0; int r = off0;
            while (wd && r < SCAN_B) { int b = __builtin_ctzll(wd); slots[r++] = lane * 64 + b; wd &= wd - 1; }
        }
        if (lane < 32) {
            unsigned long long wd = c1; int r = off1;
            while (wd && r < SCAN_B) { int b = __builtin_ctzll(wd); slots[r++] = (64 + lane) * 64 + b; wd &= wd - 1; }
        }
        asm volatile("s_waitcnt lgkmcnt(0)" ::: "memory");   // slot writes visible intra-wave
        int myPos = slots[(lane < SCAN_B) ? lane : 0];       // lane l (<nb) owns candidate l
        int myW = myPos >> 6, myB = myPos & 63;

        // --- stage candidate rows to LDS: one global_load_lds per row, one drain ---
        for (int p = 0; p < nb; ++p) {
            int P = __shfl(myPos, p, 64);
            const unsigned long long* rp = g_mask + (size_t)P * NWORDS;
            __builtin_amdgcn_global_load_lds((const uint32_t*)rp + lane * 4,
                                             (uint32_t*)&rowbuf[p][0], 16, 0, 0);
        }
        asm volatile("s_waitcnt vmcnt(0)" ::: "memory");

        // --- conflict matrix: lane l, bit p = "candidate p suppresses candidate l" ---
        uint32_t conflict = 0;
        for (int p0 = 0; p0 < nb; p0 += 8) {
            unsigned long long w[8];
            #pragma unroll
            for (int q = 0; q < 8; ++q) w[q] = rowbuf[p0 + q][myW];   // >=nb lanes read garbage, masked below
            #pragma unroll
            for (int q = 0; q < 8; ++q)
                if (p0 + q < nb) conflict |= (uint32_t)((w[q] >> myB) & 1ull) << (p0 + q);
        }
        conflict &= (lane < nb) ? ((1u << lane) - 1u) : 0u;   // only earlier candidates

        // --- serial greedy resolve: register/shfl only (~12 cy per candidate) ---
        uint32_t keptm = 0;
        for (int p = 0; p < nb; ++p) {
            uint32_t cp = (uint32_t)__shfl((int)conflict, p, 64);
            if ((cp & keptm) == 0) keptm |= 1u << p;
        }

        // --- fold kept rows into remv (pipelined LDS reads, uniform predicate) ---
        for (int p0 = 0; p0 < nb; p0 += 8) {
            #pragma unroll
            for (int q = 0; q < 8; ++q) {
                int p = p0 + q;
                if (p < nb && ((keptm >> p) & 1u)) {
                    remv0 |= rowbuf[p][lane];
                    if (lane < 32) remv1 |= rowbuf[p][64 + lane];
                    int P = __shfl(myPos, p, 64);
                    int w = P >> 6, b = P & 63;
                    if (w < 64) { if (lane == w) kept0 |= 1ull << b; }
                    else        { if (lane == w - 64) kept1 |= 1ull << b; }
                }
            }
        }
        lastPos = __shfl(myPos, nb - 1, 64);
    }

    // --- compact kept list (ascending sorted positions) into LDS ---
    int c0 = __popcll(kept0);
    int c1 = (lane < 32) ? __popcll(kept1) : 0;
    int x0 = c0, x1 = c1;
    for (int ofs = 1; ofs < 64; ofs <<= 1) {
        int y0 = __shfl_up(x0, ofs, 64);
        int y1 = __shfl_up(x1, ofs, 64);
        if (lane >= ofs) { x0 += y0; x1 += y1; }
    }
    int t0 = __shfl(x0, 63, 64);
    int t1 = __shfl(x1, 63, 64);
    int off = x0 - c0;
    unsigned long long wd = kept0;
    while (wd) { int b = __builtin_ctzll(wd); keptLds[off++] = lane * 64 + b; wd &= wd - 1; }
    off = t0 + (x1 - c1);
    wd = kept1;
    while (wd) { int b = __builtin_ctzll(wd); keptLds[off++] = (64 + lane) * 64 + b; wd &= wd - 1; }
    int K = t0 + t1;

    // ---------------- fused loss (same wave; lane = class) ----------------
    if (F == 0 || K == 0) { if (lane == 0) out[0] = 0.001f; return; }
    asm volatile("s_waitcnt lgkmcnt(0)" ::: "memory");

    int* aLds = (int*)&rowbuf[0][0];   // reuse rowbuf (scan done); capacity 8192 ints
    int npPart = 0;
    for (int k = lane; k < K; k += 64) {
        int p = keptLds[k];
        aLds[k] = g_sAnchor[p];
        npPart += g_sFi[p];
    }
    asm volatile("s_waitcnt lgkmcnt(0) vmcnt(0)" ::: "memory");
    int Kpad = (K + 7) & ~7;
    if (lane == 0) {
        int alast = aLds[K - 1];
        for (int k = K; k < Kpad; ++k) aLds[k] = alast;   // pad: strict > keeps earlier k
    }
    asm volatile("s_waitcnt lgkmcnt(0)" ::: "memory");
    for (int ofs = 32; ofs > 0; ofs >>= 1) npPart += __shfl_down(npPart, ofs, 64);
    int np = __shfl(npPart, 0, 64);

    float bv0 = -3.402823466e+38f, bv1 = -3.402823466e+38f;
    int bk0 = 0, bk1 = 0;
    for (int k0 = 0; k0 < Kpad; k0 += 8) {
        int av[8]; float va[8], vb[8];
        #pragma unroll
        for (int q = 0; q < 8; ++q) av[q] = aLds[k0 + q];       // uniform broadcast reads
        #pragma unroll
        for (int q = 0; q < 8; ++q) va[q] = conf[(size_t)av[q] * NUM_CLASSES + lane];        // 256B coalesced
        if (lane < 16) {
            #pragma unroll
            for (int q = 0; q < 8; ++q) vb[q] = conf[(size_t)av[q] * NUM_CLASSES + 64 + lane];
        }
        #pragma unroll
        for (int q = 0; q < 8; ++q)
            if (va[q] > bv0) { bv0 = va[q]; bk0 = k0 + q; }     // strict >: first max wins
        if (lane < 16) {
            #pragma unroll
            for (int q = 0; q < 8; ++q)
                if (vb[q] > bv1) { bv1 = vb[q]; bk1 = k0 + q; }
        }
    }

    float tv0 = tb[0], tv1 = tb[1], tv2 = tb[2], tv3 = tb[3];
    float s, d;
    {
        float4 bb = g_sbox[keptLds[bk0]];
        d = fabsf(bb.x - tv0); s  = (d < 1.0f) ? 0.5f * d * d : d - 0.5f;
        d = fabsf(bb.y - tv1); s += (d < 1.0f) ? 0.5f * d * d : d - 0.5f;
        d = fabsf(bb.z - tv2); s += (d < 1.0f) ? 0.5f * d * d : d - 0.5f;
        d = fabsf(bb.w - tv3); s += (d < 1.0f) ? 0.5f * d * d : d - 0.5f;
    }
    if (lane < 16) {
        float4 bb = g_sbox[keptLds[bk1]];
        d = fabsf(bb.x - tv0); s += (d < 1.0f) ? 0.5f * d * d : d - 0.5f;
        d = fabsf(bb.y - tv1); s += (d < 1.0f) ? 0.5f * d * d : d - 0.5f;
        d = fabsf(bb.z - tv2); s += (d < 1.0f) ? 0.5f * d * d : d - 0.5f;
        d = fabsf(bb.w - tv3); s += (d < 1.0f) ? 0.5f * d * d : d - 0.5f;
    }
    for (int ofs = 32; ofs > 0; ofs >>= 1) s += __shfl_down(s, ofs, 64);
    if (lane == 0) out[0] = s / (float)np;
}

extern "C" void kernel_launch(void* const* d_in, const int* in_sizes, int n_in,
                              void* d_out, int out_size, void* d_ws, size_t ws_size,
                              hipStream_t stream) {
    const float* loc  = (const float*)d_in[0];   // (1, 6144, 2)  f32
    const float* conf = (const float*)d_in[1];   // (1, 6144, 80) f32
    const float* tb   = (const float*)d_in[2];   // (1, 1, 4)     f32
    float* out = (float*)d_out;

    k_rank<<<dim3(NTILES, NTILES), 256, 0, stream>>>(conf);
    k_scatter<<<NTILES, 256, 0, stream>>>(loc, conf, tb);
    k_mask<<<(N_ANCHORS * 64) / 256, 256, 0, stream>>>();
    k_scan<<<1, 64, 0, stream>>>(conf, tb, out);
}

// Round 6
// 167.708 us; speedup vs baseline: 1.0800x; 1.0800x over previous
//
#include <hip/hip_runtime.h>
#include <stdint.h>

#define N_ANCHORS 6144
#define NUM_CLASSES 80
#define NWORDS 96   // 6144 / 64
#define NTILES 24   // 6144 / 256
#define SCAN_B 32   // candidates per scan batch
#define ROWSTRIDE 128  // ulls per LDS row (1024B: 64 lanes x 16B global_load_lds; words 96..127 = over-read pad)

// ---------------- static device scratch (avoids ws_size assumptions) ----------------
// +64 ull tail pad: width-16 staging reads 1024B per 768B row (lanes 48-63 over-read 256B on last row)
__device__ unsigned long long g_mask[(size_t)N_ANCHORS * NWORDS + 64];
__device__ float4 g_sbox[N_ANCHORS];     // sorted boxes
__device__ int    g_rpart[NTILES][N_ANCHORS]; // per-j-tile rank partials
__device__ int    g_fpart[NTILES][N_ANCHORS]; // per-j-tile filtered-index partials
__device__ int    g_sAnchor[N_ANCHORS];  // sorted pos -> anchor id
__device__ int    g_sFi[N_ANCHORS];      // sorted pos -> filtered index
__device__ int    g_keptPos[N_ANCHORS];  // compact kept list (sorted positions, ascending)
__device__ int    g_F, g_K, g_np, g_done;
__device__ float  g_loss;

// key = conf[i][0] if max(conf[i][:]) > 0.5 else -1  (exact fmax tree/order preserved)
__device__ __forceinline__ float anchor_key(const float* __restrict__ conf, int i, bool& valid) {
    const float4* cp4 = (const float4*)(conf + (size_t)i * NUM_CLASSES);
    float4 v0 = cp4[0];
    float score = v0.x;
    float m = fmaxf(fmaxf(v0.x, v0.y), fmaxf(v0.z, v0.w));
    #pragma unroll
    for (int c = 1; c < NUM_CLASSES / 4; ++c) {
        float4 v = cp4[c];
        m = fmaxf(m, fmaxf(fmaxf(v.x, v.y), fmaxf(v.z, v.w)));
    }
    valid = m > 0.5f;
    return valid ? score : -1.0f;
}

// ---------------- K1: counting-sort rank partials ----------------
// rank_i = #{valid j : key_j > key_i || (key_j == key_i && j < i)}  (stable desc sort)
// fic_i  = #{valid j : j < i}
__global__ void __launch_bounds__(256) k_rank(const float* __restrict__ conf) {
    __shared__ float skey[256];
    int y = blockIdx.y;
    int j0 = y * 256;
    bool vj;
    skey[threadIdx.x] = anchor_key(conf, j0 + threadIdx.x, vj);
    int i = blockIdx.x * 256 + threadIdx.x;
    bool vi;
    float ki = anchor_key(conf, i, vi);
    __syncthreads();
    int r = 0, f = 0;
    #pragma unroll 8
    for (int jj = 0; jj < 256; ++jj) {
        float kj = skey[jj];
        int j = j0 + jj;
        bool valid_j = kj >= 0.0f;
        r += (kj > ki) || (kj == ki && j < i && valid_j);
        f += (j < i) && valid_j;
    }
    g_rpart[y][i] = r;   // plain stores: unique (y,i) per thread
    g_fpart[y][i] = f;
}

// ---------------- K2: reduce partials + scatter into sorted order (+ F, boxes) ----------------
__global__ void __launch_bounds__(256) k_scatter(const float* __restrict__ loc,
                                                 const float* __restrict__ conf,
                                                 const float* __restrict__ tb) {
    int i = blockIdx.x * 256 + threadIdx.x;
    bool vi;
    float ki = anchor_key(conf, i, vi);
    (void)ki;
    int r = 0, f = 0;
    #pragma unroll
    for (int y = 0; y < NTILES; ++y) { r += g_rpart[y][i]; f += g_fpart[y][i]; }
    if (vi) {
        float px = loc[2 * i], py = loc[2 * i + 1];
        float4 b;
        b.x = __fmul_rn(tb[0], px);
        b.y = __fmul_rn(tb[1], py);
        b.z = __fmul_rn(tb[2], px);
        b.w = __fmul_rn(tb[3], py);
        g_sbox[r] = b;
        g_sAnchor[r] = i;
        g_sFi[r] = f;
    }
    if (i == N_ANCHORS - 1) g_F = f + (vi ? 1 : 0);   // total valid count, no atomic
}

// ---------------- K3: IoU > 0.5 bitmask, upper triangle (word >= row/64) ----------------
// NOTE: the __fdiv_rn must stay — predicate must be bit-identical to XLA's
// inter/union division; a mul-compare rewrite flips ~2 expected borderline
// pairs out of 18.9M and changes the kept set.
__global__ void __launch_bounds__(256) k_mask(void) {
    int wave = (blockIdx.x * 256 + threadIdx.x) >> 6;
    int lane = threadIdx.x & 63;
    if (wave >= N_ANCHORS) return;
    int i = wave;
    float4 bi = g_sbox[i];
    float areai = __fmul_rn(bi.z - bi.x, bi.w - bi.y);
    unsigned long long* row = g_mask + (size_t)i * NWORDS;
    for (int w = (i >> 6); w < NWORDS; ++w) {
        float4 bj = g_sbox[w * 64 + lane];
        float areaj = __fmul_rn(bj.z - bj.x, bj.w - bj.y);
        float lx = fmaxf(bi.x, bj.x), ly = fmaxf(bi.y, bj.y);
        float rx = fminf(bi.z, bj.z), ry = fminf(bi.w, bj.w);
        float iw = fmaxf(rx - lx, 0.0f), ih = fmaxf(ry - ly, 0.0f);
        float inter = __fmul_rn(iw, ih);
        float denom = __fsub_rn(__fadd_rn(areai, areaj), inter);
        float iou = __fdiv_rn(inter, denom);
        unsigned long long bits = __ballot(iou > 0.5f);
        if (lane == 0) row[w] = bits;
    }
}

// ---------------- K4: single-wave greedy-NMS scan ----------------
// r4 lesson: every __shfl(x, uniform_p) is a ~120cy ds_bpermute; ~70 serial
// instances/batch = the 48us floor. Fix: v_readlane (SALU, ~10cy) for all uniform
// broadcasts, packed 2-in-1 prefix scan, ctz-peeled groups of 8 independent LDS
// reads in the fold.
// r5 lesson: width-12 global_load_lds silently corrupted staging (absmax 8e-5);
// width 16 is the HW-verified path — keep it (ROWSTRIDE 128, g_mask tail pad).
__global__ void __launch_bounds__(64, 1) k_scan(void) {
    __shared__ alignas(16) unsigned long long rowbuf[SCAN_B][ROWSTRIDE]; // 32 KB
    __shared__ int slots[SCAN_B];
    int lane = threadIdx.x;
    int F = g_F;
    if (lane == 0) { g_loss = 0.0f; g_np = 0; g_done = 0; }   // consumed by k_loss
    if (lane < SCAN_B) slots[lane] = 0;
    auto initw = [&](int w) -> unsigned long long {
        long long lo = (long long)w * 64, hi = lo + 64;
        if (F <= lo) return ~0ull;
        if (F >= hi) return 0ull;
        return (~0ull) << (F - lo);
    };
    unsigned long long remv0 = initw(lane);                                  // word lane
    unsigned long long remv1 = (lane < 32) ? initw(64 + lane) : ~0ull;       // word 64+lane
    unsigned long long kept0 = 0, kept1 = 0;
    int lastPos = -1;

    while (true) {
        // --- extract first SCAN_B candidate positions > lastPos under current remv ---
        unsigned long long c0 = ~remv0;
        unsigned long long c1 = (lane < 32) ? ~remv1 : 0ull;
        {
            long long lo = (long long)lane << 6;
            if (lastPos >= lo + 63)      c0 = 0ull;
            else if (lastPos >= lo)      c0 &= (~0ull) << (int)(lastPos - lo + 1);
        }
        if (lane < 32) {
            long long lo = (long long)(64 + lane) << 6;
            if (lastPos >= lo + 63)      c1 = 0ull;
            else if (lastPos >= lo)      c1 &= (~0ull) << (int)(lastPos - lo + 1);
        }
        int n0 = __popcll(c0), n1 = __popcll(c1);
        // packed prefix scan: both sums in one shfl chain (each <= 6144 < 2^16, no carry-over)
        int xp = (n0 << 16) | n1;
        for (int ofs = 1; ofs < 64; ofs <<= 1) {
            int y = __shfl_up(xp, ofs, 64);
            if (lane >= ofs) xp += y;
        }
        int lastxp = __builtin_amdgcn_readlane(xp, 63);
        int tot0 = lastxp >> 16, tot1 = lastxp & 0xffff;
        int total = tot0 + tot1;
        if (total == 0) break;
        int nb = (total < SCAN_B) ? total : SCAN_B;
        int off0 = (xp >> 16) - n0;
        int off1 = tot0 + ((xp & 0xffff) - n1);
        {
            unsigned long long wd = c0; int r = off0;
            while (wd && r < SCAN_B) { int b = __builtin_ctzll(wd); slots[r++] = lane * 64 + b; wd &= wd - 1; }
        }
        if (lane < 32) {
            unsigned long long wd = c1; int r = off1;
            while (wd && r < SCAN_B) { int b = __builtin_ctzll(wd); slots[r++] = (64 + lane) * 64 + b; wd &= wd - 1; }
        }
        __syncthreads();
        int myPos = slots[(lane < SCAN_B) ? lane : 0];       // lane l (<nb) owns candidate l
        int myW = myPos >> 6, myB = myPos & 63;

        // --- stage candidate rows to LDS: width-16 (HW-verified), one drain per batch ---
        for (int p = 0; p < nb; ++p) {
            int P = __builtin_amdgcn_readlane(myPos, p);
            const unsigned long long* rp = g_mask + (size_t)P * NWORDS;
            __builtin_amdgcn_global_load_lds((const uint32_t*)rp + lane * 4,
                                             (uint32_t*)&rowbuf[p][0], 16, 0, 0);
        }
        asm volatile("s_waitcnt vmcnt(0)" ::: "memory");
        __builtin_amdgcn_sched_barrier(0);   // insurance: no LDS-read hoisting above the drain

        // --- conflict matrix: lane l, bit p = "candidate p suppresses candidate l" ---
        uint32_t conflict = 0;
        for (int p0 = 0; p0 < nb; p0 += 8) {
            unsigned long long w[8];
            #pragma unroll
            for (int q = 0; q < 8; ++q) w[q] = rowbuf[p0 + q][myW];   // stale rows masked below
            #pragma unroll
            for (int q = 0; q < 8; ++q)
                if (p0 + q < nb) conflict |= (uint32_t)((w[q] >> myB) & 1ull) << (p0 + q);
        }
        conflict &= (lane < nb) ? ((1u << lane) - 1u) : 0u;   // only earlier candidates

        // --- serial greedy resolve: readlane-only (~15 cy per candidate) ---
        uint32_t keptm = 0;
        for (int p = 0; p < nb; ++p) {
            uint32_t cp = (uint32_t)__builtin_amdgcn_readlane((int)conflict, p);
            if ((cp & keptm) == 0) keptm |= 1u << p;
        }

        // --- fold kept rows into remv: ctz-peeled groups of 8 independent LDS reads ---
        uint32_t km = keptm;
        while (km) {
            int kidx[8]; bool kv[8];
            #pragma unroll
            for (int q = 0; q < 8; ++q) {
                kv[q] = (km != 0);
                kidx[q] = kv[q] ? __builtin_ctz(km) : 0;
                if (km) km &= km - 1;
            }
            unsigned long long a0[8], a1[8];
            #pragma unroll
            for (int q = 0; q < 8; ++q) {
                a0[q] = kv[q] ? rowbuf[kidx[q]][lane] : 0ull;
                a1[q] = (kv[q] && lane < 32) ? rowbuf[kidx[q]][64 + lane] : 0ull;
            }
            #pragma unroll
            for (int q = 0; q < 8; ++q) { remv0 |= a0[q]; if (lane < 32) remv1 |= a1[q]; }
            #pragma unroll
            for (int q = 0; q < 8; ++q) {
                if (kv[q]) {
                    int P = __builtin_amdgcn_readlane(myPos, kidx[q]);
                    int w = P >> 6, b = P & 63;
                    if (w < 64) { if (lane == w) kept0 |= 1ull << b; }
                    else        { if (lane == w - 64) kept1 |= 1ull << b; }
                }
            }
        }
        lastPos = __builtin_amdgcn_readlane(myPos, nb - 1);
    }

    // --- compact kept list (ascending sorted positions) to global ---
    int c0 = __popcll(kept0);
    int c1 = (lane < 32) ? __popcll(kept1) : 0;
    int xp = (c0 << 16) | c1;
    for (int ofs = 1; ofs < 64; ofs <<= 1) {
        int y = __shfl_up(xp, ofs, 64);
        if (lane >= ofs) xp += y;
    }
    int lastxp = __builtin_amdgcn_readlane(xp, 63);
    int t0 = lastxp >> 16, t1 = lastxp & 0xffff;
    int off = (xp >> 16) - c0;
    unsigned long long wd = kept0;
    while (wd) { int b = __builtin_ctzll(wd); g_keptPos[off++] = lane * 64 + b; wd &= wd - 1; }
    off = t0 + ((xp & 0xffff) - c1);
    wd = kept1;
    while (wd) { int b = __builtin_ctzll(wd); g_keptPos[off++] = (64 + lane) * 64 + b; wd &= wd - 1; }
    if (lane == 0) g_K = t0 + t1;
}

// ---------------- K5: per-class top-1 (ties -> first kept) + smooth-L1 + num_pos
//                      + fused finalize via last-block-done counter ----------------
// Cross-block/XCD traffic all via device-scope atomics at the coherent point.
__global__ void __launch_bounds__(64) k_loss(const float* __restrict__ conf, const float* __restrict__ tb,
                                             float* __restrict__ out) {
    int c = blockIdx.x;
    int lane = threadIdx.x;
    int K = g_K;
    float bv = -3.402823466e+38f;
    int bk = 0x7fffffff;
    int np = 0;
    for (int k = lane; k < K; k += 64) {
        int p = g_keptPos[k];
        int a = g_sAnchor[p];
        float v = conf[(size_t)a * NUM_CLASSES + c];
        if (v > bv || (v == bv && k < bk)) { bv = v; bk = k; }
        if (c == 0) np += g_sFi[p];
    }
    for (int ofs = 32; ofs > 0; ofs >>= 1) {
        float ov = __shfl_down(bv, ofs, 64);
        int ok = __shfl_down(bk, ofs, 64);
        if (ov > bv || (ov == bv && ok < bk)) { bv = ov; bk = ok; }
    }
    if (c == 0) {
        for (int ofs = 32; ofs > 0; ofs >>= 1) np += __shfl_down(np, ofs, 64);
        if (lane == 0) atomicExch(&g_np, np);   // device-scope write (cross-XCD reader)
    }
    if (lane == 0) {
        if (K > 0) {
            float4 b = g_sbox[g_keptPos[bk]];
            float t0 = tb[0], t1 = tb[1], t2 = tb[2], t3 = tb[3];
            float l = 0.0f, d;
            d = fabsf(b.x - t0); l += (d < 1.0f) ? 0.5f * d * d : d - 0.5f;
            d = fabsf(b.y - t1); l += (d < 1.0f) ? 0.5f * d * d : d - 0.5f;
            d = fabsf(b.z - t2); l += (d < 1.0f) ? 0.5f * d * d : d - 0.5f;
            d = fabsf(b.w - t3); l += (d < 1.0f) ? 0.5f * d * d : d - 0.5f;
            atomicAdd(&g_loss, l);
        }
        __threadfence();                          // order my atomics before the done-count
        int done = atomicAdd(&g_done, 1);
        if (done == NUM_CLASSES - 1) {            // last block finalizes (saves a launch)
            float total = atomicAdd(&g_loss, 0.0f);   // coherent-point read
            int npv = atomicAdd(&g_np, 0);            // coherent-point read
            out[0] = (g_F == 0 || K == 0) ? 0.001f : total / (float)npv;
        }
    }
}

extern "C" void kernel_launch(void* const* d_in, const int* in_sizes, int n_in,
                              void* d_out, int out_size, void* d_ws, size_t ws_size,
                              hipStream_t stream) {
    const float* loc  = (const float*)d_in[0];   // (1, 6144, 2)  f32
    const float* conf = (const float*)d_in[1];   // (1, 6144, 80) f32
    const float* tb   = (const float*)d_in[2];   // (1, 1, 4)     f32
    float* out = (float*)d_out;

    k_rank<<<dim3(NTILES, NTILES), 256, 0, stream>>>(conf);
    k_scatter<<<NTILES, 256, 0, stream>>>(loc, conf, tb);
    k_mask<<<(N_ANCHORS * 64) / 256, 256, 0, stream>>>();
    k_scan<<<1, 64, 0, stream>>>();
    k_loss<<<NUM_CLASSES, 64, 0, stream>>>(conf, tb, out);
}